// Round 10
// baseline (836.063 us; speedup 1.0000x reference)
//
#include <hip/hip_runtime.h>
#include <hip/hip_bf16.h>

typedef __bf16 bf16_t;
typedef bf16_t bf16x8 __attribute__((ext_vector_type(8)));
typedef float f32x16 __attribute__((ext_vector_type(16)));

#define MFMA32(a, b, c) __builtin_amdgcn_mfma_f32_32x32x16_bf16(a, b, c, 0, 0, 0)

static constexpr int E_EDGE = 786432;
static constexpr int N_GRID = 262144;

// ---- edge kernel LDS geometry (BK=64, linear slots for global_load_lds) ----
static constexpr int SLOT_B = 128 * 64 * 2;      // 16384 B per slot
static constexpr int E_OFF_IDX = 67584;          // after h/outl region (128*264*2)
static constexpr int E_SMEM = E_OFF_IDX + 1536;  // 69120 -> 2 blocks/CU

// ---- node kernel LDS geometry (BK=128, padded, reg-staged) ----
static constexpr int LDT = 136;
static constexpr int ATB = 128 * LDT * 2;        // 34816
static constexpr int LDH = 264;
static constexpr int LDO = 132;
static constexpr int N_OFF_IDX = 2 * ATB;        // 69632
static constexpr int N_SMEM = N_OFF_IDX + 1536;  // 71168

#define SB __builtin_amdgcn_sched_barrier(0)
#define VMC(n) asm volatile("s_waitcnt vmcnt(" #n ")" ::: "memory")
#define LGKM_BAR do { asm volatile("s_waitcnt lgkmcnt(0)" ::: "memory"); \
    __builtin_amdgcn_s_barrier(); __builtin_amdgcn_sched_barrier(0); } while (0)

// global -> LDS async 16B: per-lane global src, wave-uniform LDS base (+lane*16 by HW)
#define GLLD16(srcp, ldsoff)                                                     \
    __builtin_amdgcn_global_load_lds(                                            \
        (const __attribute__((address_space(1))) unsigned int*)(srcp),           \
        (__attribute__((address_space(3))) unsigned int*)(unsigned int)(size_t)(ldsoff), \
        16, 0, 0)

__device__ __forceinline__ float fast_silu(float x) {
    return x * __builtin_amdgcn_rcpf(1.f + __expf(-x));
}

// out[n*K + k] = (bf16) in[k*N + n]
__global__ void transpose_to_bf16(const float* __restrict__ in, bf16_t* __restrict__ out,
                                  int K, int N) {
    int idx = blockIdx.x * 256 + threadIdx.x;
    if (idx < K * N) {
        int n = idx / K;
        int k = idx - n * K;
        out[idx] = (bf16_t)in[k * N + n];
    }
}

__global__ void f32_to_bf16_vec(const float* __restrict__ in, bf16_t* __restrict__ out, int n8) {
    int i = blockIdx.x * 256 + threadIdx.x;
    if (i < n8) {
        const float4* p = reinterpret_cast<const float4*>(in + (size_t)i * 8);
        const float4 a = p[0], b = p[1];
        union { bf16_t h[8]; uint4 u; } pk;
        pk.h[0] = (bf16_t)a.x; pk.h[1] = (bf16_t)a.y; pk.h[2] = (bf16_t)a.z; pk.h[3] = (bf16_t)a.w;
        pk.h[4] = (bf16_t)b.x; pk.h[5] = (bf16_t)b.y; pk.h[6] = (bf16_t)b.z; pk.h[7] = (bf16_t)b.w;
        reinterpret_cast<uint4*>(out)[i] = pk.u;
    }
}

// ---------------- CSR build ----------------
__global__ void k_hist(const int* __restrict__ dst, int* __restrict__ deg, int E) {
    int i = blockIdx.x * 256 + threadIdx.x;
    if (i < E) atomicAdd(&deg[dst[i]], 1);
}

__global__ void k_scan1(const int* __restrict__ deg, int* __restrict__ excl,
                        int* __restrict__ bsum) {
    __shared__ int sd[256];
    const int b = blockIdx.x, t = threadIdx.x;
    int4 v = reinterpret_cast<const int4*>(deg)[b * 256 + t];
    const int s0 = v.x, s1 = s0 + v.y, s2 = s1 + v.z, s3 = s2 + v.w;
    sd[t] = s3;
    __syncthreads();
    for (int off = 1; off < 256; off <<= 1) {
        int val = (t >= off) ? sd[t - off] : 0;
        __syncthreads();
        if (t >= off) sd[t] += val;
        __syncthreads();
    }
    const int pre = (t > 0) ? sd[t - 1] : 0;
    int4 o;
    o.x = pre; o.y = pre + s0; o.z = pre + s1; o.w = pre + s2;
    reinterpret_cast<int4*>(excl)[b * 256 + t] = o;
    if (t == 255) bsum[b] = sd[255];
}

__global__ void k_scan2(const int* __restrict__ bsum, int* __restrict__ bofs) {
    __shared__ int sd[256];
    const int t = threadIdx.x;
    sd[t] = bsum[t];
    __syncthreads();
    for (int off = 1; off < 256; off <<= 1) {
        int val = (t >= off) ? sd[t - off] : 0;
        __syncthreads();
        if (t >= off) sd[t] += val;
        __syncthreads();
    }
    bofs[t] = (t > 0) ? sd[t - 1] : 0;
}

__global__ void k_scan3(const int* __restrict__ excl, const int* __restrict__ bofs,
                        int* __restrict__ rowptr, int* __restrict__ cursor, int N, int E) {
    int i = blockIdx.x * 256 + threadIdx.x;
    if (i < N) {
        const int v = excl[i] + bofs[i >> 10];
        rowptr[i] = v;
        cursor[i] = v;
    }
    if (i == 0) rowptr[N] = E;
}

__global__ void k_slot(const int* __restrict__ dst, int* __restrict__ cursor,
                       int* __restrict__ slot, int E) {
    int i = blockIdx.x * 256 + threadIdx.x;
    if (i < E) slot[i] = atomicAdd(&cursor[dst[i]], 1);
}

// dense aggregation: aggb[n] = sum of efs rows in CSR range
__global__ __launch_bounds__(512) void k_agg(const bf16_t* __restrict__ efs,
                                             const int* __restrict__ rowptr,
                                             bf16_t* __restrict__ aggb) {
    const int node = blockIdx.x * 32 + (threadIdx.x >> 4);
    const int j = (threadIdx.x & 15) * 8;
    const int beg = rowptr[node], end = rowptr[node + 1];
    float s[8];
#pragma unroll
    for (int i = 0; i < 8; ++i) s[i] = 0.f;
    for (int e = beg; e < end; ++e) {
        bf16x8 v = *reinterpret_cast<const bf16x8*>(efs + (size_t)e * 128 + j);
#pragma unroll
        for (int i = 0; i < 8; ++i) s[i] += (float)v[i];
    }
    union { bf16_t h[8]; uint4 u; } pk;
#pragma unroll
    for (int i = 0; i < 8; ++i) pk.h[i] = (bf16_t)s[i];
    *reinterpret_cast<uint4*>(aggb + (size_t)node * 128 + j) = pk.u;
}

// ---------------- EDGE MLP: cat(m2g, mesh[src], grid[dst])[384] -> 256 SiLU -> 128 LN -> efs[slot]
// BK=64, 4 LDS slots. mesh/grid tiles staged by global_load_lds (counted vmcnt,
// XOR chunk-swizzle c^(r&7) on source + read). m2g reg-staged (slots 0,1).
// W1 frags register-prefetched 2 steps ahead (compiler-managed waits).
__global__ __launch_bounds__(512, 4) void edge_mlp(
    const float* __restrict__ m2g,
    const bf16_t* __restrict__ gridb, const bf16_t* __restrict__ meshb,
    const int* __restrict__ src_idx, const int* __restrict__ dst_idx,
    const int* __restrict__ slot,
    const bf16_t* __restrict__ W1T,  // [256][384]
    const float* __restrict__ b1,
    const bf16_t* __restrict__ W2T,  // [128][256]
    const float* __restrict__ b2,
    const float* __restrict__ g, const float* __restrict__ beta,
    bf16_t* __restrict__ efs) {
    __shared__ __align__(16) char smem[E_SMEM];

    const int tid = threadIdx.x;
    const int wave = tid >> 6, lane = tid & 63;
    const int l31 = lane & 31, lk = lane >> 5;
    const int wm = wave >> 2, wn = wave & 3;
    const int r0 = blockIdx.x * 128;
    const int srow = tid >> 2, quad = tid & 3;

    int* sidx = (int*)(smem + E_OFF_IDX);
    int* didx = sidx + 128;
    int* slotl = didx + 128;
    if (tid < 128) sidx[tid] = src_idx[r0 + tid];
    else if (tid < 256) didx[tid - 128] = dst_idx[r0 + tid - 128];
    else if (tid < 384) slotl[tid - 256] = slot[r0 + tid - 256];
    asm volatile("s_waitcnt vmcnt(0) lgkmcnt(0)" ::: "memory");
    __builtin_amdgcn_s_barrier();
    SB;

    // gll: stage one 128x64 bf16 tile (slot s) from gathered rows of tbl.
    // pass i (0,1): wave covers 8 rows; lane l -> row +(l>>3), stored chunk l&7,
    // source chunk (l&7)^(r&7)  [swizzle realized via source address]
    auto GLL = [&](const bf16_t* tbl, const int* idxl, int s, int colbase) {
#pragma unroll
        for (int i = 0; i < 2; ++i) {
            const int rr = (i * 8 + wave) * 8 + (lane >> 3);
            const int cc = (lane & 7) ^ (rr & 7);
            const bf16_t* srcp = tbl + (size_t)idxl[rr] * 128 + colbase + cc * 8;
            GLLD16(srcp, smem + s * SLOT_B + (i * 8 + wave) * 1024);
        }
    };
    auto LOADW = [&](int t, bf16x8* dst) {
        const bf16_t* wrow = W1T + (size_t)(wave * 32 + l31) * 384 + t * 64 + lk * 8;
#pragma unroll
        for (int ks = 0; ks < 4; ++ks)
            dst[ks] = *reinterpret_cast<const bf16x8*>(wrow + ks * 16);
    };

    f32x16 acc[4] = {};
    auto COMPUTE = [&](int s, const bf16x8* bf) {
        const bf16_t* A = (const bf16_t*)(smem + s * SLOT_B);
#pragma unroll
        for (int ks = 0; ks < 4; ++ks) {
            bf16x8 a[4];
#pragma unroll
            for (int mt = 0; mt < 4; ++mt) {
                const int row = mt * 32 + l31;
                a[mt] = *reinterpret_cast<const bf16x8*>(
                    A + row * 64 + ((ks * 2 + lk) ^ (row & 7)) * 8);
            }
#pragma unroll
            for (int mt = 0; mt < 4; ++mt)
                acc[mt] = MFMA32(a[mt], bf[ks], acc[mt]);
        }
    };

    // ---- prologue: m2g(8), W1(0)(4), W1(1)(4), gll mesh(2+2) ----
    float4 f0[8];
    {
        const float* p0 = m2g + (size_t)(r0 + srow) * 128 + quad * 32;
#pragma unroll
        for (int j = 0; j < 8; ++j)
            f0[j] = *reinterpret_cast<const float4*>(p0 + j * 4);
    }
    SB;
    bf16x8 bfr0[4], bfr1[4], bfr2[4];
    LOADW(0, bfr0);
    LOADW(1, bfr1);
    SB;
    GLL(meshb, sidx, 2, 0);
    GLL(meshb, sidx, 3, 64);
    SB;
    VMC(12);  // m2g done (12 = W1(0)4 + W1(1)4 + gll4 after it)
    // stage slots 0,1 from m2g regs (cvt + swizzled ds_write)
    {
        const int s = quad >> 1, hf = quad & 1;
        bf16_t* sl = (bf16_t*)(smem + s * SLOT_B) + srow * 64;
#pragma unroll
        for (int j = 0; j < 4; ++j) {
            union { bf16_t h[8]; uint4 u; } pk;
            const float4 v0 = f0[j * 2], v1 = f0[j * 2 + 1];
            pk.h[0] = (bf16_t)v0.x; pk.h[1] = (bf16_t)v0.y;
            pk.h[2] = (bf16_t)v0.z; pk.h[3] = (bf16_t)v0.w;
            pk.h[4] = (bf16_t)v1.x; pk.h[5] = (bf16_t)v1.y;
            pk.h[6] = (bf16_t)v1.z; pk.h[7] = (bf16_t)v1.w;
            const int st = ((hf * 4 + j) ^ (srow & 7));
            *reinterpret_cast<uint4*>(sl + st * 8) = pk.u;
        }
    }
    VMC(8);  // W1(0) done (8 = W1(1)4 + gll4)
    LGKM_BAR;

    // t0: m2g-lo
    LOADW(2, bfr2); SB;
    COMPUTE(0, bfr0);
    VMC(8);  // W1(1) done (gll4 + W1(2)4)
    LGKM_BAR;
    // t1: m2g-hi
    LOADW(3, bfr0); SB;
    GLL(gridb, didx, 0, 0); SB;
    COMPUTE(1, bfr1);
    VMC(6);  // mesh-lo + W1(2) done (W1(3)4 + g-lo2)
    LGKM_BAR;
    // t2: mesh-lo
    LOADW(4, bfr1); SB;
    GLL(gridb, didx, 1, 64); SB;
    COMPUTE(2, bfr2);
    VMC(8);  // mesh-hi + W1(3) done (g-lo2 + W1(4)4 + g-hi2)
    LGKM_BAR;
    // t3: mesh-hi
    LOADW(5, bfr2); SB;
    COMPUTE(3, bfr0);
    VMC(6);  // g-lo + W1(4) done (g-hi2 + W1(5)4)
    LGKM_BAR;
    // t4: grid-lo
    COMPUTE(0, bfr1);
    VMC(0);  // g-hi + W1(5) done
    LGKM_BAR;
    // t5: grid-hi
    COMPUTE(1, bfr2);
    LGKM_BAR;

    // ---- bias + SiLU -> h [128][LDH] bf16 (overlaps slot region) ----
    bf16_t* hT = (bf16_t*)smem;
    {
        const int col = wave * 32 + l31;
        const float bb = b1[col];
#pragma unroll
        for (int mt = 0; mt < 4; ++mt)
#pragma unroll
            for (int r = 0; r < 16; ++r) {
                const int row = mt * 32 + (r & 3) + 8 * (r >> 2) + 4 * lk;
                hT[row * LDH + col] = (bf16_t)fast_silu(acc[mt][r] + bb);
            }
    }
    LGKM_BAR;

    // ---- GEMM2: [128,256] x [256,128]; W2 in regs ----
    bf16x8 b2f[16];
#pragma unroll
    for (int ks = 0; ks < 16; ++ks)
        b2f[ks] = *reinterpret_cast<const bf16x8*>(
            W2T + (size_t)(wn * 32 + l31) * 256 + ks * 16 + lk * 8);

    f32x16 acc2[2] = {};
#pragma unroll
    for (int ks = 0; ks < 16; ++ks) {
        const int kb = ks * 16 + lk * 8;
        bf16x8 a[2];
#pragma unroll
        for (int mt = 0; mt < 2; ++mt)
            a[mt] = *reinterpret_cast<const bf16x8*>(hT + (wm * 64 + mt * 32 + l31) * LDH + kb);
#pragma unroll
        for (int mt = 0; mt < 2; ++mt)
            acc2[mt] = MFMA32(a[mt], b2f[ks], acc2[mt]);
    }
    LGKM_BAR;

    // ---- bias -> outl [128][LDO] f32 ----
    float* outl = (float*)smem;
    {
        const int col = wn * 32 + l31;
        const float bb = b2[col];
#pragma unroll
        for (int mt = 0; mt < 2; ++mt)
#pragma unroll
            for (int r = 0; r < 16; ++r) {
                const int row = wm * 64 + mt * 32 + (r & 3) + 8 * (r >> 2) + 4 * lk;
                outl[row * LDO + col] = acc2[mt][r] + bb;
            }
    }
    LGKM_BAR;

    // ---- LayerNorm (4 threads/row) + bf16 row store to efs[slot] ----
    {
        const int lrow = tid >> 2, lq = (tid & 3) * 32;
        const float* rpd = outl + lrow * LDO + lq;
        float s = 0.f, sq2 = 0.f;
#pragma unroll
        for (int q = 0; q < 8; ++q) {
            const float4 v = *reinterpret_cast<const float4*>(rpd + q * 4);
            s += v.x + v.y + v.z + v.w;
            sq2 += v.x * v.x + v.y * v.y + v.z * v.z + v.w * v.w;
        }
        s += __shfl_xor(s, 1);  sq2 += __shfl_xor(sq2, 1);
        s += __shfl_xor(s, 2);  sq2 += __shfl_xor(sq2, 2);
        const float mean = s * (1.f / 128.f);
        const float var = sq2 * (1.f / 128.f) - mean * mean;
        const float rstd = rsqrtf(var + 1e-5f);

        const int sl = slotl[lrow];
        bf16_t* op = efs + (size_t)sl * 128 + lq;
        union { bf16_t h[32]; uint4 u[4]; } pk;
#pragma unroll
        for (int q = 0; q < 8; ++q) {
            const float4 v = *reinterpret_cast<const float4*>(rpd + q * 4);
            const float4 gv = *reinterpret_cast<const float4*>(g + lq + q * 4);
            const float4 bv = *reinterpret_cast<const float4*>(beta + lq + q * 4);
            pk.h[q * 4 + 0] = (bf16_t)((v.x - mean) * rstd * gv.x + bv.x);
            pk.h[q * 4 + 1] = (bf16_t)((v.y - mean) * rstd * gv.y + bv.y);
            pk.h[q * 4 + 2] = (bf16_t)((v.z - mean) * rstd * gv.z + bv.z);
            pk.h[q * 4 + 3] = (bf16_t)((v.w - mean) * rstd * gv.w + bv.w);
        }
#pragma unroll
        for (int j = 0; j < 4; ++j)
            *reinterpret_cast<uint4*>(op + j * 8) = pk.u[j];
    }
}

// ---------------- NODE MLP: cat(agg, grid)[256] -> 256 SiLU -> 128 LN + residual -> out
template <bool DENSE>
__global__ __launch_bounds__(512, 4) void node_mlp(
    const bf16_t* __restrict__ aggb,
    const bf16_t* __restrict__ efs,
    const int* __restrict__ rowptr,
    const bf16_t* __restrict__ gridb,
    const float* __restrict__ gridf,
    const bf16_t* __restrict__ W1T,    // [256][256]
    const float* __restrict__ b1,
    const bf16_t* __restrict__ W2T,    // [128][256]
    const float* __restrict__ b2,
    const float* __restrict__ g, const float* __restrict__ beta,
    float* __restrict__ outp) {
    __shared__ __align__(16) char smem[N_SMEM];

    const int tid = threadIdx.x;
    const int wave = tid >> 6, lane = tid & 63;
    const int l31 = lane & 31, lk = lane >> 5;
    const int wm = wave >> 2, wn = wave & 3;
    const int r0 = blockIdx.x * 128;
    const int srow = tid >> 2, sc = (tid & 3) * 32;

    bf16_t* buf0 = (bf16_t*)smem;
    bf16_t* buf1 = (bf16_t*)(smem + ATB);
    int* rp = (int*)(smem + N_OFF_IDX);

    uint4 a0[4];
    if constexpr (DENSE) {
        const bf16_t* p0 = aggb + (size_t)(r0 + srow) * 128 + sc;
#pragma unroll
        for (int j = 0; j < 4; ++j) a0[j] = *reinterpret_cast<const uint4*>(p0 + j * 8);
    } else {
        if (tid < 129) rp[tid] = rowptr[r0 + tid];
        asm volatile("s_waitcnt lgkmcnt(0)" ::: "memory");
        __builtin_amdgcn_s_barrier();
        const int beg = rp[srow], end = rp[srow + 1];
        float s[32];
#pragma unroll
        for (int i = 0; i < 32; ++i) s[i] = 0.f;
        for (int e = beg; e < end; ++e) {
            const bf16_t* p = efs + (size_t)e * 128 + sc;
#pragma unroll
            for (int q = 0; q < 4; ++q) {
                bf16x8 v = *reinterpret_cast<const bf16x8*>(p + q * 8);
#pragma unroll
                for (int i = 0; i < 8; ++i) s[q * 8 + i] += (float)v[i];
            }
        }
#pragma unroll
        for (int q = 0; q < 4; ++q) {
            union { bf16_t h[8]; uint4 u; } pk;
#pragma unroll
            for (int i = 0; i < 8; ++i) pk.h[i] = (bf16_t)s[q * 8 + i];
            a0[q] = pk.u;
        }
    }
    uint4 a1[4];
    {
        const bf16_t* p1 = gridb + (size_t)(r0 + srow) * 128 + sc;
#pragma unroll
        for (int j = 0; j < 4; ++j) a1[j] = *reinterpret_cast<const uint4*>(p1 + j * 8);
    }
    const bf16_t* wrow = W1T + (size_t)(wave * 32 + l31) * 256 + lk * 8;
    bf16x8 bfr[8];
#pragma unroll
    for (int ks = 0; ks < 8; ++ks) bfr[ks] = *reinterpret_cast<const bf16x8*>(wrow + ks * 16);

    {
        bf16_t* dst = buf0 + srow * LDT + sc;
#pragma unroll
        for (int j = 0; j < 4; ++j) *reinterpret_cast<uint4*>(dst + j * 8) = a0[j];
    }
    asm volatile("s_waitcnt lgkmcnt(0)" ::: "memory");
    __builtin_amdgcn_s_barrier();
    SB;

    f32x16 acc[4] = {};
    auto COMPUTE = [&](const bf16_t* A) {
#pragma unroll
        for (int ks = 0; ks < 8; ++ks) {
            const int kb = ks * 16 + lk * 8;
            bf16x8 a[4];
#pragma unroll
            for (int mt = 0; mt < 4; ++mt)
                a[mt] = *reinterpret_cast<const bf16x8*>(A + (mt * 32 + l31) * LDT + kb);
#pragma unroll
            for (int mt = 0; mt < 4; ++mt)
                acc[mt] = MFMA32(a[mt], bfr[ks], acc[mt]);
        }
    };

    {
        bf16_t* dst = buf1 + srow * LDT + sc;
#pragma unroll
        for (int j = 0; j < 4; ++j) *reinterpret_cast<uint4*>(dst + j * 8) = a1[j];
    }
    COMPUTE(buf0);
#pragma unroll
    for (int ks = 0; ks < 8; ++ks)
        bfr[ks] = *reinterpret_cast<const bf16x8*>(wrow + 128 + ks * 16);
    asm volatile("s_waitcnt lgkmcnt(0)" ::: "memory");
    __builtin_amdgcn_s_barrier();
    SB;
    COMPUTE(buf1);
    asm volatile("s_waitcnt lgkmcnt(0)" ::: "memory");
    __builtin_amdgcn_s_barrier();
    SB;

    bf16_t* hT = (bf16_t*)smem;
    {
        const int col = wave * 32 + l31;
        const float bb = b1[col];
#pragma unroll
        for (int mt = 0; mt < 4; ++mt)
#pragma unroll
            for (int r = 0; r < 16; ++r) {
                const int row = mt * 32 + (r & 3) + 8 * (r >> 2) + 4 * lk;
                hT[row * LDH + col] = (bf16_t)fast_silu(acc[mt][r] + bb);
            }
    }
    asm volatile("s_waitcnt lgkmcnt(0)" ::: "memory");
    __builtin_amdgcn_s_barrier();
    SB;

    bf16x8 b2f[16];
#pragma unroll
    for (int ks = 0; ks < 16; ++ks)
        b2f[ks] = *reinterpret_cast<const bf16x8*>(
            W2T + (size_t)(wn * 32 + l31) * 256 + ks * 16 + lk * 8);

    f32x16 acc2[2] = {};
#pragma unroll
    for (int ks = 0; ks < 16; ++ks) {
        const int kb = ks * 16 + lk * 8;
        bf16x8 a[2];
#pragma unroll
        for (int mt = 0; mt < 2; ++mt)
            a[mt] = *reinterpret_cast<const bf16x8*>(hT + (wm * 64 + mt * 32 + l31) * LDH + kb);
#pragma unroll
        for (int mt = 0; mt < 2; ++mt)
            acc2[mt] = MFMA32(a[mt], b2f[ks], acc2[mt]);
    }
    asm volatile("s_waitcnt lgkmcnt(0)" ::: "memory");
    __builtin_amdgcn_s_barrier();
    SB;

    float* outl = (float*)smem;
    {
        const int col = wn * 32 + l31;
        const float bb = b2[col];
#pragma unroll
        for (int mt = 0; mt < 2; ++mt)
#pragma unroll
            for (int r = 0; r < 16; ++r) {
                const int row = wm * 64 + mt * 32 + (r & 3) + 8 * (r >> 2) + 4 * lk;
                outl[row * LDO + col] = acc2[mt][r] + bb;
            }
    }
    asm volatile("s_waitcnt lgkmcnt(0)" ::: "memory");
    __builtin_amdgcn_s_barrier();
    SB;

    {
        const int lrow = tid >> 2, lq = (tid & 3) * 32;
        const float* rpd = outl + lrow * LDO + lq;
        float s = 0.f, sq2 = 0.f;
#pragma unroll
        for (int q = 0; q < 8; ++q) {
            const float4 v = *reinterpret_cast<const float4*>(rpd + q * 4);
            s += v.x + v.y + v.z + v.w;
            sq2 += v.x * v.x + v.y * v.y + v.z * v.z + v.w * v.w;
        }
        s += __shfl_xor(s, 1);  sq2 += __shfl_xor(sq2, 1);
        s += __shfl_xor(s, 2);  sq2 += __shfl_xor(sq2, 2);
        const float mean = s * (1.f / 128.f);
        const float var = sq2 * (1.f / 128.f) - mean * mean;
        const float rstd = rsqrtf(var + 1e-5f);

        const float* grp = gridf + (size_t)(r0 + lrow) * 128 + lq;
        float* op = outp + (size_t)(r0 + lrow) * 128 + lq;
#pragma unroll
        for (int q = 0; q < 8; ++q) {
            const float4 v = *reinterpret_cast<const float4*>(rpd + q * 4);
            const float4 gv = *reinterpret_cast<const float4*>(g + lq + q * 4);
            const float4 bv = *reinterpret_cast<const float4*>(beta + lq + q * 4);
            const float4 rr = *reinterpret_cast<const float4*>(grp + q * 4);
            float4 y;
            y.x = (v.x - mean) * rstd * gv.x + bv.x + rr.x;
            y.y = (v.y - mean) * rstd * gv.y + bv.y + rr.y;
            y.z = (v.z - mean) * rstd * gv.z + bv.z + rr.z;
            y.w = (v.w - mean) * rstd * gv.w + bv.w + rr.w;
            *reinterpret_cast<float4*>(op + q * 4) = y;
        }
    }
}

extern "C" void kernel_launch(void* const* d_in, const int* in_sizes, int n_in,
                              void* d_out, int out_size, void* d_ws, size_t ws_size,
                              hipStream_t stream) {
    const float* m2g = (const float*)d_in[0];
    const float* gridf = (const float*)d_in[1];
    const float* meshf = (const float*)d_in[2];
    const int* src_idx = (const int*)d_in[3];
    const int* dst_idx = (const int*)d_in[4];
    const float* eW1 = (const float*)d_in[5];
    const float* eb1 = (const float*)d_in[6];
    const float* eW2 = (const float*)d_in[7];
    const float* eb2 = (const float*)d_in[8];
    const float* eg = (const float*)d_in[9];
    const float* ebeta = (const float*)d_in[10];
    const float* nW1 = (const float*)d_in[11];
    const float* nb1 = (const float*)d_in[12];
    const float* nW2 = (const float*)d_in[13];
    const float* nb2 = (const float*)d_in[14];
    const float* ng = (const float*)d_in[15];
    const float* nbeta = (const float*)d_in[16];
    float* out = (float*)d_out;

    const size_t mesh_elems = (size_t)in_sizes[2];
    const size_t grid_elems = (size_t)N_GRID * 128;
    const size_t efs_elems = (size_t)E_EDGE * 128;

    char* base = (char*)d_ws;
    size_t off = 0;
    auto alloc = [&](size_t bytes) { size_t o = off; off = (off + bytes + 15) & ~(size_t)15; return o; };

    const size_t o_w1e = alloc(256 * 384 * 2);
    const size_t o_w2e = alloc(128 * 256 * 2);
    const size_t o_w1n = alloc(256 * 256 * 2);
    const size_t o_w2n = alloc(128 * 256 * 2);
    const size_t o_gridb = alloc(grid_elems * 2);
    const size_t o_meshb = alloc(mesh_elems * 2);
    const size_t o_efs = alloc(efs_elems * 2);
    const size_t o_rowptr = alloc((N_GRID + 1) * 4);
    const size_t o_cursor = alloc((size_t)N_GRID * 4);
    const size_t o_slot = alloc((size_t)E_EDGE * 4);
    const size_t o_deg = alloc((size_t)N_GRID * 4);
    const size_t o_excl = alloc((size_t)N_GRID * 4);
    const size_t o_bsum = alloc(256 * 4);
    const size_t o_bofs = alloc(256 * 4);
    const size_t o_aggb = alloc(grid_elems * 2);
    const size_t need_dense = off;

    bf16_t* W1eT = (bf16_t*)(base + o_w1e);
    bf16_t* W2eT = (bf16_t*)(base + o_w2e);
    bf16_t* W1nT = (bf16_t*)(base + o_w1n);
    bf16_t* W2nT = (bf16_t*)(base + o_w2n);
    bf16_t* gridb = (bf16_t*)(base + o_gridb);
    bf16_t* meshb = (bf16_t*)(base + o_meshb);
    bf16_t* efs = (bf16_t*)(base + o_efs);
    int* rowptr = (int*)(base + o_rowptr);
    int* cursor = (int*)(base + o_cursor);
    int* slot = (int*)(base + o_slot);
    int* deg = (int*)(base + o_deg);
    int* excl = (int*)(base + o_excl);
    int* bsum = (int*)(base + o_bsum);
    int* bofs = (int*)(base + o_bofs);
    bf16_t* aggb = (bf16_t*)(base + o_aggb);

    const bool dense = ws_size >= need_dense;

    transpose_to_bf16<<<(384 * 256 + 255) / 256, 256, 0, stream>>>(eW1, W1eT, 384, 256);
    transpose_to_bf16<<<(256 * 128 + 255) / 256, 256, 0, stream>>>(eW2, W2eT, 256, 128);
    transpose_to_bf16<<<(256 * 256 + 255) / 256, 256, 0, stream>>>(nW1, W1nT, 256, 256);
    transpose_to_bf16<<<(256 * 128 + 255) / 256, 256, 0, stream>>>(nW2, W2nT, 256, 128);

    const int g8 = (int)(grid_elems / 8), m8 = (int)(mesh_elems / 8);
    f32_to_bf16_vec<<<(g8 + 255) / 256, 256, 0, stream>>>(gridf, gridb, g8);
    f32_to_bf16_vec<<<(m8 + 255) / 256, 256, 0, stream>>>(meshf, meshb, m8);

    hipMemsetAsync(deg, 0, (size_t)N_GRID * 4, stream);
    k_hist<<<(E_EDGE + 255) / 256, 256, 0, stream>>>(dst_idx, deg, E_EDGE);
    k_scan1<<<256, 256, 0, stream>>>(deg, excl, bsum);
    k_scan2<<<1, 256, 0, stream>>>(bsum, bofs);
    k_scan3<<<(N_GRID + 255) / 256, 256, 0, stream>>>(excl, bofs, rowptr, cursor, N_GRID, E_EDGE);
    k_slot<<<(E_EDGE + 255) / 256, 256, 0, stream>>>(dst_idx, cursor, slot, E_EDGE);

    edge_mlp<<<E_EDGE / 128, 512, 0, stream>>>(
        m2g, gridb, meshb, src_idx, dst_idx, slot,
        W1eT, eb1, W2eT, eb2, eg, ebeta, efs);

    if (dense) {
        k_agg<<<N_GRID / 32, 512, 0, stream>>>(efs, rowptr, aggb);
        node_mlp<true><<<N_GRID / 128, 512, 0, stream>>>(
            aggb, nullptr, nullptr, gridb, gridf,
            W1nT, nb1, W2nT, nb2, ng, nbeta, out);
    } else {
        node_mlp<false><<<N_GRID / 128, 512, 0, stream>>>(
            nullptr, efs, rowptr, gridb, gridf,
            W1nT, nb1, W2nT, nb2, ng, nbeta, out);
    }
}